// Round 7
// baseline (606.727 us; speedup 1.0000x reference)
//
#include <hip/hip_runtime.h>

#define NN   10000
#define FIN  4096
#define HID  1024
#define CO   20
#define EE   160000
#define ET   170000           // EE + NN (self loops appended)
#define NBV  (HID + 22)       // 1046 valid B rows: Ws1 | W0 | ws1v | wd1v

typedef __bf16 bf16x8 __attribute__((ext_vector_type(8)));
typedef float  f32x4  __attribute__((ext_vector_type(4)));

__device__ __forceinline__ float bf2f(unsigned short u) {
    unsigned int x = ((unsigned int)u) << 16;
    float f; __builtin_memcpy(&f, &x, 4); return f;
}
__device__ __forceinline__ unsigned short f2bf(float f) {
    unsigned int x; __builtin_memcpy(&x, &f, 4);
    unsigned int r = (x + 0x7fffu + ((x >> 16) & 1u)) >> 16;
    return (unsigned short)r;
}
__device__ __forceinline__ void unpack4(int2 v, float* f) {
    unsigned int a = (unsigned int)v.x, b = (unsigned int)v.y;
    f[0] = bf2f((unsigned short)(a & 0xffffu)); f[1] = bf2f((unsigned short)(a >> 16));
    f[2] = bf2f((unsigned short)(b & 0xffffu)); f[3] = bf2f((unsigned short)(b >> 16));
}
__device__ __forceinline__ int edge_at(const int* __restrict__ e, int idx, int is64) {
    return is64 ? e[2 * (size_t)idx] : e[idx];
}
__device__ __forceinline__ int4 pack8(float4 a, float4 b) {
    int4 o;
    o.x = (int)((unsigned)f2bf(a.x) | ((unsigned)f2bf(a.y) << 16));
    o.y = (int)((unsigned)f2bf(a.z) | ((unsigned)f2bf(a.w) << 16));
    o.z = (int)((unsigned)f2bf(b.x) | ((unsigned)f2bf(b.y) << 16));
    o.w = (int)((unsigned)f2bf(b.z) | ((unsigned)f2bf(b.w) << 16));
    return o;
}

// ------- fp32 -> bf16 cast (8 elems/thread) + cnt zero + edge-dtype sniff -------
__global__ void k_cast(const float* __restrict__ src, unsigned short* __restrict__ dst,
                       const int* __restrict__ edg, int* __restrict__ cnt,
                       int* __restrict__ flag) {
    int i = blockIdx.x * 256 + threadIdx.x;   // grid is exactly NN*FIN/8/256 blocks
    const float4* s = (const float4*)src + (size_t)i * 2;
    *(int4*)(dst + (size_t)i * 8) = pack8(s[0], s[1]);
    if (i < NN) cnt[i] = 0;
    if (i < 64) {                              // wave 0 of block 0
        int v = edg[2 * i + 1];
        unsigned long long bm = __ballot(v != 0);
        if (i == 0) flag[0] = (bm == 0ull) ? 1 : 0;
    }
}

// ------- fused: Bext rows 0..1043 pack (bf16)  |  attention-vector fold partials ----
#define BEXTB 2088    // (HID+CO)*(FIN/8)/256
__global__ __launch_bounds__(256) void k_prep(const float* __restrict__ Ws1,
                                              const float* __restrict__ Wd1,
                                              const float* __restrict__ W0,
                                              const float* __restrict__ as1,
                                              const float* __restrict__ ad1,
                                              unsigned short* __restrict__ Bext,
                                              float* __restrict__ partS,
                                              float* __restrict__ partD) {
    if (blockIdx.x < BEXTB) {
        int i = blockIdx.x * 256 + threadIdx.x;
        int row = i >> 9;               // / 512
        int col = (i & 511) * 8;
        const float* src = (row < HID) ? Ws1 + (size_t)row * FIN
                                       : W0 + (size_t)(row - HID) * FIN;
        const float4* s = (const float4*)(src + col);
        *(int4*)(Bext + (size_t)row * FIN + col) = pack8(s[0], s[1]);
    } else {
        int bx = blockIdx.x - BEXTB;              // 0..127
        int k = (bx & 15) * 256 + threadIdx.x;    // 0..4095
        int chunk = bx >> 4;                      // 0..7
        int r0 = chunk * 128;
        float s = 0.f, d = 0.f;
        for (int r = r0; r < r0 + 128; r++) {
            s += as1[r] * Ws1[(size_t)r * FIN + k];
            d += ad1[r] * Wd1[(size_t)r * FIN + k];
        }
        partS[chunk * FIN + k] = s;
        partD[chunk * FIN + k] = d;
    }
}

// reduce partials; write ws1v/wd1v straight into Bext rows 1044/1045; compute wd2v
__global__ void k_vred(const float* __restrict__ partS, const float* __restrict__ partD,
                       const float* __restrict__ Wd2, const float* __restrict__ ad2,
                       unsigned short* __restrict__ Bext, float* __restrict__ wd2v) {
    int k = blockIdx.x * 256 + threadIdx.x;
    if (k < FIN) {
        float s = 0.f, d = 0.f;
        for (int j = 0; j < 8; j++) { s += partS[j * FIN + k]; d += partD[j * FIN + k]; }
        Bext[(size_t)(HID + CO) * FIN + k]     = f2bf(s);
        Bext[(size_t)(HID + CO + 1) * FIN + k] = f2bf(d);
    }
    if (k < HID) {
        float d2 = 0.f;
        for (int r = 0; r < CO; r++) d2 += ad2[r] * Wd2[(size_t)r * HID + k];
        wd2v[k] = d2;
    }
}

// ---------------- MFMA GEMM (128x128, XCD-chunk swizzle) ----------
// Launched TWICE over m-halves (diagnostic: lowers top-5 threshold to ~76us so any
// hidden >76us kernel surfaces in rocprof). Swizzle uses gridDim.x (bijective any grid).
// C[Mloc, 1046] = A @ B^T. Cols <HID -> H1 bf16; cols HID.. -> extp fp32 [22][NN] slab.
#define GBM 128
#define GBN 128
#define GBK 32
#define NNT ((NBV + GBN - 1) / GBN)   // 9 n-tiles

__global__ __launch_bounds__(256) void k_gemm_ext(
    const unsigned short* __restrict__ A, const unsigned short* __restrict__ B,
    unsigned short* __restrict__ H1, float* __restrict__ extp, int M) {
    __shared__ __bf16 As[2][GBM * GBK];
    __shared__ __bf16 Bs[2][GBN * GBK];
    int nwg = gridDim.x;
    int bid = blockIdx.x;
    int q = nwg >> 3, r = nwg & 7;
    int xcd = bid & 7, idx = bid >> 3;
    int swz = (xcd < r ? xcd * (q + 1) : r * (q + 1) + (xcd - r) * q) + idx;
    int mt = swz / NNT;
    int nt = swz - mt * NNT;
    int m0 = mt * GBM;
    int n0 = nt * GBN;
    int tid = threadIdx.x;
    int lane = tid & 63, wave = tid >> 6;
    int wm = (wave >> 1) * 64, wn = (wave & 1) * 64;
    int lrow = lane & 15, lk8 = (lane >> 4) * 8;

    int srow = lane >> 2;
    int scol = (lane & 3) * 8;
    int arow = wave * 32;
    int gmA0 = m0 + arow + srow;      if (gmA0 >= M) gmA0 = M - 1;
    int gmA1 = m0 + arow + 16 + srow; if (gmA1 >= M) gmA1 = M - 1;
    int gnB0 = n0 + arow + srow;      if (gnB0 >= NBV) gnB0 = NBV - 1;
    int gnB1 = n0 + arow + 16 + srow; if (gnB1 >= NBV) gnB1 = NBV - 1;
    const unsigned short* pA0 = A + (size_t)gmA0 * FIN + scol;
    const unsigned short* pA1 = A + (size_t)gmA1 * FIN + scol;
    const unsigned short* pB0 = B + (size_t)gnB0 * FIN + scol;
    const unsigned short* pB1 = B + (size_t)gnB1 * FIN + scol;

    f32x4 acc[4][4];
#pragma unroll
    for (int r2 = 0; r2 < 4; r2++)
#pragma unroll
        for (int c = 0; c < 4; c++) acc[r2][c] = (f32x4){0.f, 0.f, 0.f, 0.f};

    auto stage = [&](int buf, int k0) {
        __builtin_amdgcn_global_load_lds(
            (const __attribute__((address_space(1))) void*)(pA0 + k0),
            (__attribute__((address_space(3))) void*)&As[buf][arow * GBK], 16, 0, 0);
        __builtin_amdgcn_global_load_lds(
            (const __attribute__((address_space(1))) void*)(pA1 + k0),
            (__attribute__((address_space(3))) void*)&As[buf][(arow + 16) * GBK], 16, 0, 0);
        __builtin_amdgcn_global_load_lds(
            (const __attribute__((address_space(1))) void*)(pB0 + k0),
            (__attribute__((address_space(3))) void*)&Bs[buf][arow * GBK], 16, 0, 0);
        __builtin_amdgcn_global_load_lds(
            (const __attribute__((address_space(1))) void*)(pB1 + k0),
            (__attribute__((address_space(3))) void*)&Bs[buf][(arow + 16) * GBK], 16, 0, 0);
    };

    stage(0, 0);
    int cur = 0;
    for (int k0 = 0; k0 < FIN; k0 += GBK) {
        __syncthreads();
        if (k0 + GBK < FIN) stage(cur ^ 1, k0 + GBK);
        bf16x8 af[4], bfr[4];
#pragma unroll
        for (int r2 = 0; r2 < 4; r2++)
            af[r2] = *(const bf16x8*)(&As[cur][(wm + r2 * 16 + lrow) * GBK + lk8]);
#pragma unroll
        for (int c = 0; c < 4; c++)
            bfr[c] = *(const bf16x8*)(&Bs[cur][(wn + c * 16 + lrow) * GBK + lk8]);
#pragma unroll
        for (int r2 = 0; r2 < 4; r2++)
#pragma unroll
            for (int c = 0; c < 4; c++)
                acc[r2][c] = __builtin_amdgcn_mfma_f32_16x16x32_bf16(af[r2], bfr[c], acc[r2][c], 0, 0, 0);
        cur ^= 1;
    }
    int orow = (lane >> 4) * 4, ocol = lane & 15;
#pragma unroll
    for (int r2 = 0; r2 < 4; r2++)
#pragma unroll
        for (int c = 0; c < 4; c++)
#pragma unroll
            for (int i = 0; i < 4; i++) {
                int m = m0 + wm + r2 * 16 + orow + i;
                int n = n0 + wn + c * 16 + ocol;
                if (m < M) {
                    float v = acc[r2][c][i];
                    if (n < HID)      H1[(size_t)m * HID + n] = f2bf(v);
                    else if (n < NBV) extp[(size_t)(n - HID) * NN + m] = v;
                }
            }
}

// ------- fused: CSR degree count  |  per-class softmax stats over ext rows -------
#define CNTB 665    // (ET+255)/256
__global__ __launch_bounds__(256) void k_cfs(const int* __restrict__ edges,
                                             const int* __restrict__ flag,
                                             int* __restrict__ cnt,
                                             const float* __restrict__ ext,
                                             float* __restrict__ gmax,
                                             float* __restrict__ ginv) {
    if (blockIdx.x < CNTB) {
        int k = blockIdx.x * 256 + threadIdx.x;
        if (k >= ET) return;
        int is64 = flag[0];
        int d = (k < EE) ? edge_at(edges, EE + k, is64) : (k - EE);
        if ((unsigned)d < NN) atomicAdd(&cnt[d], 1);
    } else {
        int c = blockIdx.x - CNTB, t = threadIdx.x, lane = t & 63, wv = t >> 6;
        const float* row = ext + (size_t)c * NN;
        __shared__ float r4[4];
        __shared__ float bv;
        float m = -INFINITY;
        for (int n = t; n < NN; n += 256) m = fmaxf(m, row[n]);
        for (int o = 32; o; o >>= 1) m = fmaxf(m, __shfl_xor(m, o, 64));
        if (lane == 0) r4[wv] = m;
        __syncthreads();
        if (t == 0) bv = fmaxf(fmaxf(r4[0], r4[1]), fmaxf(r4[2], r4[3]));
        __syncthreads();
        float gm = bv;
        __syncthreads();
        float s = 0.f;
        for (int n = t; n < NN; n += 256) s += expf(row[n] - gm);
        for (int o = 32; o; o >>= 1) s += __shfl_xor(s, o, 64);
        if (lane == 0) r4[wv] = s;
        __syncthreads();
        if (t == 0) { gmax[c] = gm; ginv[c] = 1.0f / (r4[0] + r4[1] + r4[2] + r4[3]); }
    }
}

// 1024 threads x 10 elems each; shfl scan, 2 barriers
__global__ __launch_bounds__(1024) void k_scan(const int* __restrict__ cnt,
                                               int* __restrict__ offs,
                                               int* __restrict__ cursor) {
    int t = threadIdx.x, lane = t & 63, wv = t >> 6;
    int base = t * 10;
    int c[10]; int tot = 0;
    if (base < NN) {
#pragma unroll
        for (int j = 0; j < 10; j++) { c[j] = cnt[base + j]; tot += c[j]; }
    }
    int incl = tot;
#pragma unroll
    for (int o = 1; o < 64; o <<= 1) {
        int v = __shfl_up(incl, o, 64);
        if (lane >= o) incl += v;
    }
    __shared__ int wsum[16];
    if (lane == 63) wsum[wv] = incl;
    __syncthreads();
    if (t < 16) {
        int v = wsum[t];
        int inc2 = v;
#pragma unroll
        for (int o = 1; o < 16; o <<= 1) {
            int u = __shfl_up(inc2, o, 64);
            if (t >= o) inc2 += u;
        }
        wsum[t] = inc2 - v;  // exclusive wave offset
    }
    __syncthreads();
    int excl = incl - tot + wsum[wv];
    if (base < NN) {
        int run = excl;
#pragma unroll
        for (int j = 0; j < 10; j++) {
            cursor[base + j] = run;
            run += c[j];
            offs[base + j + 1] = run;
        }
    }
    if (t == 0) offs[0] = 0;
}

__global__ void k_scatter(const int* __restrict__ edges, const int* __restrict__ flag,
                          int* __restrict__ cursor, int* __restrict__ csr_src) {
    int k = blockIdx.x * 256 + threadIdx.x;
    if (k >= ET) return;
    int is64 = flag[0];
    int s, d;
    if (k < EE) { s = edge_at(edges, k, is64); d = edge_at(edges, EE + k, is64); }
    else        { s = d = k - EE; }
    if ((unsigned)d >= NN) return;
    if ((unsigned)s >= NN) s = 0;
    int pos = atomicAdd(&cursor[d], 1);
    csr_src[pos] = s;
}

// ------- fused: edge softmax + layer-1 agg + bias + ELU + H2/a_src2/a_dst2 -------
// Round-4 form (measured best): wave-per-node, lane owns 16 H1 cols via two
// coalesced int4 loads per edge; (src, alpha) cached in LDS.
__global__ __launch_bounds__(64) void k_agg1f(
    const int* __restrict__ offs, const int* __restrict__ csr,
    const float* __restrict__ a_src, const float* __restrict__ a_dst,
    const unsigned short* __restrict__ H1,
    const float* __restrict__ b1, const float* __restrict__ Ws2,
    const float* __restrict__ wd2v, const float* __restrict__ as2,
    float* __restrict__ H2, float* __restrict__ a_src2, float* __restrict__ a_dst2) {
    int n = blockIdx.x, lane = threadIdx.x;
    int b = offs[n], deg = offs[n + 1] - b;
    float ad = a_dst[n];
    __shared__ int   sc[128];
    __shared__ float av[128];
    bool small = (deg <= 128);
    float gm, inv;
    if (small) {
        float mymax = -INFINITY;
        for (int j = lane; j < deg; j += 64) {
            int s = csr[b + j];
            float v = a_src[s] + ad;
            v = (v >= 0.f) ? v : 0.2f * v;
            sc[j] = s; av[j] = v;
            mymax = fmaxf(mymax, v);
        }
        for (int o = 32; o; o >>= 1) mymax = fmaxf(mymax, __shfl_xor(mymax, o, 64));
        gm = mymax;
        float mysum = 0.f;
        for (int j = lane; j < deg; j += 64) {
            float e = expf(av[j] - gm);
            av[j] = e;
            mysum += e;
        }
        for (int o = 32; o; o >>= 1) mysum += __shfl_xor(mysum, o, 64);
        inv = 1.0f / (mysum + 1e-16f);
        for (int j = lane; j < deg; j += 64) av[j] *= inv;
        __syncthreads();
    } else {
        float mymax = -INFINITY;
        for (int j = lane; j < deg; j += 64) {
            float v = a_src[csr[b + j]] + ad;
            v = (v >= 0.f) ? v : 0.2f * v;
            mymax = fmaxf(mymax, v);
        }
        for (int o = 32; o; o >>= 1) mymax = fmaxf(mymax, __shfl_xor(mymax, o, 64));
        gm = mymax;
        float mysum = 0.f;
        for (int j = lane; j < deg; j += 64) {
            float v = a_src[csr[b + j]] + ad;
            v = (v >= 0.f) ? v : 0.2f * v;
            mysum += expf(v - gm);
        }
        for (int o = 32; o; o >>= 1) mysum += __shfl_xor(mysum, o, 64);
        inv = 1.0f / (mysum + 1e-16f);
    }
    float acc[16];
#pragma unroll
    for (int i = 0; i < 16; i++) acc[i] = 0.f;
    for (int base = 0; base < deg; base += 128) {
        int lim = deg - base; if (lim > 128) lim = 128;
        if (!small) {
            __syncthreads();
            for (int j = lane; j < lim; j += 64) {
                int s = csr[b + base + j];
                float v = a_src[s] + ad;
                v = (v >= 0.f) ? v : 0.2f * v;
                sc[j] = s; av[j] = expf(v - gm) * inv;
            }
            __syncthreads();
        }
        for (int j = 0; j < lim; j++) {
            int s = sc[j]; float w = av[j];
            const unsigned short* hp = H1 + (size_t)s * HID + lane * 8;
            int4 p0 = *(const int4*)hp;          // cols lane*8 .. +7
            int4 p1 = *(const int4*)(hp + 512);  // cols 512+lane*8 .. +7
            float f[8];
            unpack4(make_int2(p0.x, p0.y), f);
            unpack4(make_int2(p0.z, p0.w), f + 4);
#pragma unroll
            for (int i = 0; i < 8; i++) acc[i] += w * f[i];
            unpack4(make_int2(p1.x, p1.y), f);
            unpack4(make_int2(p1.z, p1.w), f + 4);
#pragma unroll
            for (int i = 0; i < 8; i++) acc[8 + i] += w * f[i];
        }
    }
    // bias + ELU
    float xf[16];
    {
        const float4* bp0 = (const float4*)(b1 + lane * 8);
        const float4* bp1 = (const float4*)(b1 + 512 + lane * 8);
        float4 c0 = bp0[0], c1 = bp0[1], c2 = bp1[0], c3 = bp1[1];
        float bb[16] = {c0.x,c0.y,c0.z,c0.w, c1.x,c1.y,c1.z,c1.w,
                        c2.x,c2.y,c2.z,c2.w, c3.x,c3.y,c3.z,c3.w};
#pragma unroll
        for (int i = 0; i < 16; i++) {
            float v = acc[i] + bb[i];
            xf[i] = (v > 0.f) ? v : (expf(v) - 1.f);
        }
    }
    // projection to 21 outputs, wave-local reduce
    float a2 = 0.f;
    for (int c = 0; c < 21; c++) {
        const float* wr = (c < CO) ? Ws2 + (size_t)c * HID : wd2v;
        const float4* w0 = (const float4*)(wr + lane * 8);
        const float4* w1 = (const float4*)(wr + 512 + lane * 8);
        float4 wa = w0[0], wb = w0[1], wc = w1[0], wd = w1[1];
        float dp = xf[0]*wa.x + xf[1]*wa.y + xf[2]*wa.z + xf[3]*wa.w
                 + xf[4]*wb.x + xf[5]*wb.y + xf[6]*wb.z + xf[7]*wb.w
                 + xf[8]*wc.x + xf[9]*wc.y + xf[10]*wc.z + xf[11]*wc.w
                 + xf[12]*wd.x + xf[13]*wd.y + xf[14]*wd.z + xf[15]*wd.w;
        for (int o = 32; o; o >>= 1) dp += __shfl_xor(dp, o, 64);
        if (c < CO) {
            if (lane == 0) H2[(size_t)n * CO + c] = dp;
            a2 += dp * as2[c];
        } else if (lane == 0) a_dst2[n] = dp;
    }
    if (lane == 0) a_src2[n] = a2;
}

// ------- fused: edge softmax (alpha2) + layer-2 aggregation + bias -> ms1T ----------
// Wave-per-node; both half-waves MAC in parallel (even/odd edges), shfl_xor(32) combine.
__global__ __launch_bounds__(64) void k_agg2(const int* __restrict__ offs,
                                             const int* __restrict__ csr,
                                             const float* __restrict__ a_src,
                                             const float* __restrict__ a_dst,
                                             const float* __restrict__ H2,
                                             const float* __restrict__ b2,
                                             float* __restrict__ ms1T) {
    int n = blockIdx.x, lane = threadIdx.x;
    int b = offs[n], deg = offs[n + 1] - b;
    float ad = a_dst[n];
    __shared__ int   sc[128];
    __shared__ float av[128];
    bool small = (deg <= 128);
    float gm, inv;
    if (small) {
        float mymax = -INFINITY;
        for (int j = lane; j < deg; j += 64) {
            int s = csr[b + j];
            float v = a_src[s] + ad;
            v = (v >= 0.f) ? v : 0.2f * v;
            sc[j] = s; av[j] = v;
            mymax = fmaxf(mymax, v);
        }
        for (int o = 32; o; o >>= 1) mymax = fmaxf(mymax, __shfl_xor(mymax, o, 64));
        gm = mymax;
        float mysum = 0.f;
        for (int j = lane; j < deg; j += 64) {
            float e = expf(av[j] - gm);
            av[j] = e;
            mysum += e;
        }
        for (int o = 32; o; o >>= 1) mysum += __shfl_xor(mysum, o, 64);
        inv = 1.0f / (mysum + 1e-16f);
        for (int j = lane; j < deg; j += 64) av[j] *= inv;
        __syncthreads();
    } else {
        float mymax = -INFINITY;
        for (int j = lane; j < deg; j += 64) {
            float v = a_src[csr[b + j]] + ad;
            v = (v >= 0.f) ? v : 0.2f * v;
            mymax = fmaxf(mymax, v);
        }
        for (int o = 32; o; o >>= 1) mymax = fmaxf(mymax, __shfl_xor(mymax, o, 64));
        gm = mymax;
        float mysum = 0.f;
        for (int j = lane; j < deg; j += 64) {
            float v = a_src[csr[b + j]] + ad;
            v = (v >= 0.f) ? v : 0.2f * v;
            mysum += expf(v - gm);
        }
        for (int o = 32; o; o >>= 1) mysum += __shfl_xor(mysum, o, 64);
        inv = 1.0f / (mysum + 1e-16f);
    }
    int h = lane >> 5, c = lane & 31;
    float acc = 0.f;
    for (int base = 0; base < deg; base += 128) {
        int lim = deg - base; if (lim > 128) lim = 128;
        if (!small) {
            __syncthreads();
            for (int j = lane; j < lim; j += 64) {
                int s = csr[b + base + j];
                float v = a_src[s] + ad;
                v = (v >= 0.f) ? v : 0.2f * v;
                sc[j] = s; av[j] = expf(v - gm) * inv;
            }
            __syncthreads();
        }
        if (c < CO)
            for (int j = h; j < lim; j += 2)
                acc += av[j] * H2[(size_t)sc[j] * CO + c];
    }
    acc += __shfl_xor(acc, 32, 64);
    if (h == 0 && c < CO) ms1T[(size_t)c * NN + n] = acc + b2[c];
}

// ------- final out0 + new_edge in one kernel -------
__global__ __launch_bounds__(256) void k_fout(const float* __restrict__ ext,
                                              const float* __restrict__ ms1T,
                                              const float* __restrict__ gmax,
                                              const float* __restrict__ ginv,
                                              const int* __restrict__ edges,
                                              const int* __restrict__ flag,
                                              float* __restrict__ out) {
    int g = blockIdx.x * 256 + threadIdx.x;
    if (g < NN) {
        float o[CO];
#pragma unroll
        for (int c = 0; c < CO; c++)
            o[c] = expf(ext[(size_t)c * NN + g] - gmax[c]) * ginv[c] * ms1T[(size_t)c * NN + g];
#pragma unroll
        for (int c = 0; c < CO; c += 4) {
            float4 v; v.x = o[c]; v.y = o[c + 1]; v.z = o[c + 2]; v.w = o[c + 3];
            *(float4*)(out + (size_t)g * CO + c) = v;
        }
    }
    if (g < ET) {
        int is64 = flag[0];
        int s, d;
        if (g < EE) { s = edge_at(edges, g, is64); d = edge_at(edges, EE + g, is64); }
        else        { s = d = g - EE; }
        out[NN * CO + g]      = bf2f(f2bf((float)s));
        out[NN * CO + ET + g] = bf2f(f2bf((float)d));
    }
}

extern "C" void kernel_launch(void* const* d_in, const int* in_sizes, int n_in,
                              void* d_out, int out_size, void* d_ws, size_t ws_size,
                              hipStream_t stream) {
    const float* x   = (const float*)d_in[0];
    const int*   edg = (const int*)d_in[1];
    const float* W0  = (const float*)d_in[2];
    const float* Ws1 = (const float*)d_in[4];
    const float* Wd1 = (const float*)d_in[5];
    const float* as1 = (const float*)d_in[6];
    const float* ad1 = (const float*)d_in[7];
    const float* b1  = (const float*)d_in[8];
    const float* Ws2 = (const float*)d_in[9];
    const float* Wd2 = (const float*)d_in[10];
    const float* as2 = (const float*)d_in[11];
    const float* ad2 = (const float*)d_in[12];
    const float* b2  = (const float*)d_in[13];
    float* out = (float*)d_out;

    char* p = (char*)d_ws;
    auto alloc = [&](size_t bytes) -> char* {
        char* r = p; p += (bytes + 511) & ~((size_t)511); return r;
    };
    unsigned short* xb   = (unsigned short*)alloc((size_t)NN * FIN * 2);   // 81.9 MB
    unsigned short* Bext = (unsigned short*)alloc((size_t)NBV * FIN * 2);  //  8.6 MB
    unsigned short* H1   = (unsigned short*)alloc((size_t)NN * HID * 2);   // 20.5 MB
    float* ext    = (float*)alloc((size_t)22 * NN * 4);   // ms0T rows 0..19, a_src1=20, a_dst1=21
    float* partS  = (float*)alloc((size_t)8 * FIN * 4);
    float* partD  = (float*)alloc((size_t)8 * FIN * 4);
    float* wd2v   = (float*)alloc(HID * 4);
    float* H2     = (float*)alloc((size_t)NN * CO * 4);
    float* ms1T   = (float*)alloc((size_t)CO * NN * 4);
    float* a_src2 = (float*)alloc(NN * 4);
    float* a_dst2 = (float*)alloc(NN * 4);
    int* csr_src  = (int*)alloc((size_t)ET * 4);
    int* cnt      = (int*)alloc(NN * 4);
    int* offs     = (int*)alloc((NN + 1) * 4);
    int* cursor   = (int*)alloc(NN * 4);
    int* eflag    = (int*)alloc(64);
    float* gmax   = (float*)alloc(CO * 4);
    float* ginv   = (float*)alloc(CO * 4);

    k_cast<<<NN * FIN / 8 / 256, 256, 0, stream>>>(x, xb, edg, cnt, eflag);
    k_prep<<<BEXTB + 128, 256, 0, stream>>>(Ws1, Wd1, W0, as1, ad1, Bext, partS, partD);
    k_vred<<<FIN / 256, 256, 0, stream>>>(partS, partD, Wd2, ad2, Bext, wd2v);
    // GEMM in two m-halves: rows [0,5120) and [5120,10000)
    k_gemm_ext<<<40 * NNT, 256, 0, stream>>>(xb, Bext, H1, ext, 5120);
    k_gemm_ext<<<39 * NNT, 256, 0, stream>>>(xb + (size_t)5120 * FIN, Bext,
                                             H1 + (size_t)5120 * HID, ext + 5120, 4880);
    k_cfs<<<CNTB + CO, 256, 0, stream>>>(edg, eflag, cnt, ext, gmax, ginv);
    k_scan<<<1, 1024, 0, stream>>>(cnt, offs, cursor);
    k_scatter<<<(ET + 255) / 256, 256, 0, stream>>>(edg, eflag, cursor, csr_src);
    k_agg1f<<<NN, 64, 0, stream>>>(offs, csr_src, ext + 20 * NN, ext + 21 * NN, H1,
                                   b1, Ws2, wd2v, as2, H2, a_src2, a_dst2);
    k_agg2<<<NN, 64, 0, stream>>>(offs, csr_src, a_src2, a_dst2, H2, b2, ms1T);
    k_fout<<<(ET + 255) / 256, 256, 0, stream>>>(ext, ms1T, gmax, ginv, edg, eflag, out);
}

// Round 8
// 531.037 us; speedup vs baseline: 1.1425x; 1.1425x over previous
//
#include <hip/hip_runtime.h>

#define NN   10000
#define FIN  4096
#define HID  1024
#define CO   20
#define EE   160000
#define ET   170000           // EE + NN (self loops appended)
#define NBV  (HID + 22)       // 1046 valid B rows: Ws1 | W0 | ws1v | wd1v

typedef __bf16 bf16x8 __attribute__((ext_vector_type(8)));
typedef float  f32x4  __attribute__((ext_vector_type(4)));

__device__ __forceinline__ float bf2f(unsigned short u) {
    unsigned int x = ((unsigned int)u) << 16;
    float f; __builtin_memcpy(&f, &x, 4); return f;
}
__device__ __forceinline__ unsigned short f2bf(float f) {
    unsigned int x; __builtin_memcpy(&x, &f, 4);
    unsigned int r = (x + 0x7fffu + ((x >> 16) & 1u)) >> 16;
    return (unsigned short)r;
}
__device__ __forceinline__ void unpack4(int2 v, float* f) {
    unsigned int a = (unsigned int)v.x, b = (unsigned int)v.y;
    f[0] = bf2f((unsigned short)(a & 0xffffu)); f[1] = bf2f((unsigned short)(a >> 16));
    f[2] = bf2f((unsigned short)(b & 0xffffu)); f[3] = bf2f((unsigned short)(b >> 16));
}
__device__ __forceinline__ int edge_at(const int* __restrict__ e, int idx, int is64) {
    return is64 ? e[2 * (size_t)idx] : e[idx];
}
__device__ __forceinline__ int4 pack8(float4 a, float4 b) {
    int4 o;
    o.x = (int)((unsigned)f2bf(a.x) | ((unsigned)f2bf(a.y) << 16));
    o.y = (int)((unsigned)f2bf(a.z) | ((unsigned)f2bf(a.w) << 16));
    o.z = (int)((unsigned)f2bf(b.x) | ((unsigned)f2bf(b.y) << 16));
    o.w = (int)((unsigned)f2bf(b.z) | ((unsigned)f2bf(b.w) << 16));
    return o;
}

// ------- fp32 -> bf16 cast (8 elems/thread) + cnt zero + edge-dtype sniff -------
__global__ void k_cast(const float* __restrict__ src, unsigned short* __restrict__ dst,
                       const int* __restrict__ edg, int* __restrict__ cnt,
                       int* __restrict__ flag) {
    int i = blockIdx.x * 256 + threadIdx.x;   // grid is exactly NN*FIN/8/256 blocks
    const float4* s = (const float4*)src + (size_t)i * 2;
    *(int4*)(dst + (size_t)i * 8) = pack8(s[0], s[1]);
    if (i < NN) cnt[i] = 0;
    if (i < 64) {                              // wave 0 of block 0
        int v = edg[2 * i + 1];
        unsigned long long bm = __ballot(v != 0);
        if (i == 0) flag[0] = (bm == 0ull) ? 1 : 0;
    }
}

// --- fused: Bext pack | attention-vector fold partials | CSR degree count ---
// (count is safe here: cnt was zeroed by k_cast, a PRIOR launch on the same stream)
#define BEXTB 2088    // (HID+CO)*(FIN/8)/256
#define CNTB  665     // (ET+255)/256
__global__ __launch_bounds__(256) void k_prep(const float* __restrict__ Ws1,
                                              const float* __restrict__ Wd1,
                                              const float* __restrict__ W0,
                                              const float* __restrict__ as1,
                                              const float* __restrict__ ad1,
                                              unsigned short* __restrict__ Bext,
                                              float* __restrict__ partS,
                                              float* __restrict__ partD,
                                              const int* __restrict__ edges,
                                              const int* __restrict__ flag,
                                              int* __restrict__ cnt) {
    if (blockIdx.x < BEXTB) {
        int i = blockIdx.x * 256 + threadIdx.x;
        int row = i >> 9;               // / 512
        int col = (i & 511) * 8;
        const float* src = (row < HID) ? Ws1 + (size_t)row * FIN
                                       : W0 + (size_t)(row - HID) * FIN;
        const float4* s = (const float4*)(src + col);
        *(int4*)(Bext + (size_t)row * FIN + col) = pack8(s[0], s[1]);
    } else if (blockIdx.x < BEXTB + 128) {
        int bx = blockIdx.x - BEXTB;              // 0..127
        int k = (bx & 15) * 256 + threadIdx.x;    // 0..4095
        int chunk = bx >> 4;                      // 0..7
        int r0 = chunk * 128;
        float s = 0.f, d = 0.f;
        for (int r = r0; r < r0 + 128; r++) {
            s += as1[r] * Ws1[(size_t)r * FIN + k];
            d += ad1[r] * Wd1[(size_t)r * FIN + k];
        }
        partS[chunk * FIN + k] = s;
        partD[chunk * FIN + k] = d;
    } else {
        int k = (blockIdx.x - BEXTB - 128) * 256 + threadIdx.x;
        if (k >= ET) return;
        int is64 = flag[0];
        int d = (k < EE) ? edge_at(edges, EE + k, is64) : (k - EE);
        if ((unsigned)d < NN) atomicAdd(&cnt[d], 1);
    }
}

// reduce partials; write ws1v/wd1v straight into Bext rows 1044/1045; compute wd2v
__global__ void k_vred(const float* __restrict__ partS, const float* __restrict__ partD,
                       const float* __restrict__ Wd2, const float* __restrict__ ad2,
                       unsigned short* __restrict__ Bext, float* __restrict__ wd2v) {
    int k = blockIdx.x * 256 + threadIdx.x;
    if (k < FIN) {
        float s = 0.f, d = 0.f;
        for (int j = 0; j < 8; j++) { s += partS[j * FIN + k]; d += partD[j * FIN + k]; }
        Bext[(size_t)(HID + CO) * FIN + k]     = f2bf(s);
        Bext[(size_t)(HID + CO + 1) * FIN + k] = f2bf(d);
    }
    if (k < HID) {
        float d2 = 0.f;
        for (int r = 0; r < CO; r++) d2 += ad2[r] * Wd2[(size_t)r * HID + k];
        wd2v[k] = d2;
    }
}

// ---------------- MFMA GEMM (128x128, XCD-chunk swizzle, single 711-block launch) ----
// C[M, 1046] = xb @ Bext^T. Cols <HID -> H1 bf16 [M][HID]; cols HID..HID+21 -> ext fp32 [22][NN].
#define GBM 128
#define GBN 128
#define GBK 32
#define NMT ((NN + GBM - 1) / GBM)    // 79 m-tiles
#define NNT ((NBV + GBN - 1) / GBN)   // 9 n-tiles
#define NWG (NMT * NNT)               // 711 blocks

__global__ __launch_bounds__(256) void k_gemm_ext(
    const unsigned short* __restrict__ A, const unsigned short* __restrict__ B,
    unsigned short* __restrict__ H1, float* __restrict__ ext, int M) {
    __shared__ __bf16 As[2][GBM * GBK];
    __shared__ __bf16 Bs[2][GBN * GBK];
    int bid = blockIdx.x;
    int q = NWG >> 3, r = NWG & 7;
    int xcd = bid & 7, idx = bid >> 3;
    int swz = (xcd < r ? xcd * (q + 1) : r * (q + 1) + (xcd - r) * q) + idx;
    int mt = swz / NNT;
    int nt = swz - mt * NNT;
    int m0 = mt * GBM;
    int n0 = nt * GBN;
    int tid = threadIdx.x;
    int lane = tid & 63, wave = tid >> 6;
    int wm = (wave >> 1) * 64, wn = (wave & 1) * 64;
    int lrow = lane & 15, lk8 = (lane >> 4) * 8;

    int srow = lane >> 2;
    int scol = (lane & 3) * 8;
    int arow = wave * 32;
    int gmA0 = m0 + arow + srow;      if (gmA0 >= M) gmA0 = M - 1;
    int gmA1 = m0 + arow + 16 + srow; if (gmA1 >= M) gmA1 = M - 1;
    int gnB0 = n0 + arow + srow;      if (gnB0 >= NBV) gnB0 = NBV - 1;
    int gnB1 = n0 + arow + 16 + srow; if (gnB1 >= NBV) gnB1 = NBV - 1;
    const unsigned short* pA0 = A + (size_t)gmA0 * FIN + scol;
    const unsigned short* pA1 = A + (size_t)gmA1 * FIN + scol;
    const unsigned short* pB0 = B + (size_t)gnB0 * FIN + scol;
    const unsigned short* pB1 = B + (size_t)gnB1 * FIN + scol;

    f32x4 acc[4][4];
#pragma unroll
    for (int r2 = 0; r2 < 4; r2++)
#pragma unroll
        for (int c = 0; c < 4; c++) acc[r2][c] = (f32x4){0.f, 0.f, 0.f, 0.f};

    auto stage = [&](int buf, int k0) {
        __builtin_amdgcn_global_load_lds(
            (const __attribute__((address_space(1))) void*)(pA0 + k0),
            (__attribute__((address_space(3))) void*)&As[buf][arow * GBK], 16, 0, 0);
        __builtin_amdgcn_global_load_lds(
            (const __attribute__((address_space(1))) void*)(pA1 + k0),
            (__attribute__((address_space(3))) void*)&As[buf][(arow + 16) * GBK], 16, 0, 0);
        __builtin_amdgcn_global_load_lds(
            (const __attribute__((address_space(1))) void*)(pB0 + k0),
            (__attribute__((address_space(3))) void*)&Bs[buf][arow * GBK], 16, 0, 0);
        __builtin_amdgcn_global_load_lds(
            (const __attribute__((address_space(1))) void*)(pB1 + k0),
            (__attribute__((address_space(3))) void*)&Bs[buf][(arow + 16) * GBK], 16, 0, 0);
    };

    stage(0, 0);
    int cur = 0;
    for (int k0 = 0; k0 < FIN; k0 += GBK) {
        __syncthreads();
        if (k0 + GBK < FIN) stage(cur ^ 1, k0 + GBK);
        bf16x8 af[4], bfr[4];
#pragma unroll
        for (int r2 = 0; r2 < 4; r2++)
            af[r2] = *(const bf16x8*)(&As[cur][(wm + r2 * 16 + lrow) * GBK + lk8]);
#pragma unroll
        for (int c = 0; c < 4; c++)
            bfr[c] = *(const bf16x8*)(&Bs[cur][(wn + c * 16 + lrow) * GBK + lk8]);
#pragma unroll
        for (int r2 = 0; r2 < 4; r2++)
#pragma unroll
            for (int c = 0; c < 4; c++)
                acc[r2][c] = __builtin_amdgcn_mfma_f32_16x16x32_bf16(af[r2], bfr[c], acc[r2][c], 0, 0, 0);
        cur ^= 1;
    }
    int orow = (lane >> 4) * 4, ocol = lane & 15;
#pragma unroll
    for (int r2 = 0; r2 < 4; r2++)
#pragma unroll
        for (int c = 0; c < 4; c++)
#pragma unroll
            for (int i = 0; i < 4; i++) {
                int m = m0 + wm + r2 * 16 + orow + i;
                int n = n0 + wn + c * 16 + ocol;
                if (m < M) {
                    float v = acc[r2][c][i];
                    if (n < HID)      H1[(size_t)m * HID + n] = f2bf(v);
                    else if (n < NBV) ext[(size_t)(n - HID) * NN + m] = v;
                }
            }
}

// 1024 threads x 10 elems each; shfl scan, 2 barriers
__global__ __launch_bounds__(1024) void k_scan(const int* __restrict__ cnt,
                                               int* __restrict__ offs,
                                               int* __restrict__ cursor) {
    int t = threadIdx.x, lane = t & 63, wv = t >> 6;
    int base = t * 10;
    int c[10]; int tot = 0;
    if (base < NN) {
#pragma unroll
        for (int j = 0; j < 10; j++) { c[j] = cnt[base + j]; tot += c[j]; }
    }
    int incl = tot;
#pragma unroll
    for (int o = 1; o < 64; o <<= 1) {
        int v = __shfl_up(incl, o, 64);
        if (lane >= o) incl += v;
    }
    __shared__ int wsum[16];
    if (lane == 63) wsum[wv] = incl;
    __syncthreads();
    if (t < 16) {
        int v = wsum[t];
        int inc2 = v;
#pragma unroll
        for (int o = 1; o < 16; o <<= 1) {
            int u = __shfl_up(inc2, o, 64);
            if (t >= o) inc2 += u;
        }
        wsum[t] = inc2 - v;  // exclusive wave offset
    }
    __syncthreads();
    int excl = incl - tot + wsum[wv];
    if (base < NN) {
        int run = excl;
#pragma unroll
        for (int j = 0; j < 10; j++) {
            cursor[base + j] = run;
            run += c[j];
            offs[base + j + 1] = run;
        }
    }
    if (t == 0) offs[0] = 0;
}

// ------- fused: CSR scatter + new_edge output copy  |  per-class softmax stats -------
__global__ __launch_bounds__(256) void k_scatter(const int* __restrict__ edges,
                                                 const int* __restrict__ flag,
                                                 int* __restrict__ cursor,
                                                 int* __restrict__ csr_src,
                                                 const float* __restrict__ ext,
                                                 float* __restrict__ gmax,
                                                 float* __restrict__ ginv,
                                                 float* __restrict__ out) {
    if (blockIdx.x < CNTB) {
        int k = blockIdx.x * 256 + threadIdx.x;
        if (k >= ET) return;
        int is64 = flag[0];
        int s, d;
        if (k < EE) { s = edge_at(edges, k, is64); d = edge_at(edges, EE + k, is64); }
        else        { s = d = k - EE; }
        out[NN * CO + k]      = bf2f(f2bf((float)s));   // new_edge row 0
        out[NN * CO + ET + k] = bf2f(f2bf((float)d));   // new_edge row 1
        if ((unsigned)d >= NN) return;
        if ((unsigned)s >= NN) s = 0;
        int pos = atomicAdd(&cursor[d], 1);
        csr_src[pos] = s;
    } else {
        int c = blockIdx.x - CNTB, t = threadIdx.x, lane = t & 63, wv = t >> 6;
        const float* row = ext + (size_t)c * NN;
        __shared__ float r4[4];
        __shared__ float bv;
        float m = -INFINITY;
        for (int n = t; n < NN; n += 256) m = fmaxf(m, row[n]);
        for (int o = 32; o; o >>= 1) m = fmaxf(m, __shfl_xor(m, o, 64));
        if (lane == 0) r4[wv] = m;
        __syncthreads();
        if (t == 0) bv = fmaxf(fmaxf(r4[0], r4[1]), fmaxf(r4[2], r4[3]));
        __syncthreads();
        float gm = bv;
        __syncthreads();
        float s = 0.f;
        for (int n = t; n < NN; n += 256) s += expf(row[n] - gm);
        for (int o = 32; o; o >>= 1) s += __shfl_xor(s, o, 64);
        if (lane == 0) r4[wv] = s;
        __syncthreads();
        if (t == 0) { gmax[c] = gm; ginv[c] = 1.0f / (r4[0] + r4[1] + r4[2] + r4[3]); }
    }
}

// ------- fused: edge softmax + layer-1 agg + bias + ELU + H2/a_src2/a_dst2 -------
// Round-4 form (measured best): wave-per-node, lane owns 16 H1 cols via two
// coalesced int4 loads per edge; (src, alpha) cached in LDS.
__global__ __launch_bounds__(64) void k_agg1f(
    const int* __restrict__ offs, const int* __restrict__ csr,
    const float* __restrict__ a_src, const float* __restrict__ a_dst,
    const unsigned short* __restrict__ H1,
    const float* __restrict__ b1, const float* __restrict__ Ws2,
    const float* __restrict__ wd2v, const float* __restrict__ as2,
    float* __restrict__ H2, float* __restrict__ a_src2, float* __restrict__ a_dst2) {
    int n = blockIdx.x, lane = threadIdx.x;
    int b = offs[n], deg = offs[n + 1] - b;
    float ad = a_dst[n];
    __shared__ int   sc[128];
    __shared__ float av[128];
    bool small = (deg <= 128);
    float gm, inv;
    if (small) {
        float mymax = -INFINITY;
        for (int j = lane; j < deg; j += 64) {
            int s = csr[b + j];
            float v = a_src[s] + ad;
            v = (v >= 0.f) ? v : 0.2f * v;
            sc[j] = s; av[j] = v;
            mymax = fmaxf(mymax, v);
        }
        for (int o = 32; o; o >>= 1) mymax = fmaxf(mymax, __shfl_xor(mymax, o, 64));
        gm = mymax;
        float mysum = 0.f;
        for (int j = lane; j < deg; j += 64) {
            float e = expf(av[j] - gm);
            av[j] = e;
            mysum += e;
        }
        for (int o = 32; o; o >>= 1) mysum += __shfl_xor(mysum, o, 64);
        inv = 1.0f / (mysum + 1e-16f);
        for (int j = lane; j < deg; j += 64) av[j] *= inv;
        __syncthreads();
    } else {
        float mymax = -INFINITY;
        for (int j = lane; j < deg; j += 64) {
            float v = a_src[csr[b + j]] + ad;
            v = (v >= 0.f) ? v : 0.2f * v;
            mymax = fmaxf(mymax, v);
        }
        for (int o = 32; o; o >>= 1) mymax = fmaxf(mymax, __shfl_xor(mymax, o, 64));
        gm = mymax;
        float mysum = 0.f;
        for (int j = lane; j < deg; j += 64) {
            float v = a_src[csr[b + j]] + ad;
            v = (v >= 0.f) ? v : 0.2f * v;
            mysum += expf(v - gm);
        }
        for (int o = 32; o; o >>= 1) mysum += __shfl_xor(mysum, o, 64);
        inv = 1.0f / (mysum + 1e-16f);
    }
    float acc[16];
#pragma unroll
    for (int i = 0; i < 16; i++) acc[i] = 0.f;
    for (int base = 0; base < deg; base += 128) {
        int lim = deg - base; if (lim > 128) lim = 128;
        if (!small) {
            __syncthreads();
            for (int j = lane; j < lim; j += 64) {
                int s = csr[b + base + j];
                float v = a_src[s] + ad;
                v = (v >= 0.f) ? v : 0.2f * v;
                sc[j] = s; av[j] = expf(v - gm) * inv;
            }
            __syncthreads();
        }
        for (int j = 0; j < lim; j++) {
            int s = sc[j]; float w = av[j];
            const unsigned short* hp = H1 + (size_t)s * HID + lane * 8;
            int4 p0 = *(const int4*)hp;          // cols lane*8 .. +7
            int4 p1 = *(const int4*)(hp + 512);  // cols 512+lane*8 .. +7
            float f[8];
            unpack4(make_int2(p0.x, p0.y), f);
            unpack4(make_int2(p0.z, p0.w), f + 4);
#pragma unroll
            for (int i = 0; i < 8; i++) acc[i] += w * f[i];
            unpack4(make_int2(p1.x, p1.y), f);
            unpack4(make_int2(p1.z, p1.w), f + 4);
#pragma unroll
            for (int i = 0; i < 8; i++) acc[8 + i] += w * f[i];
        }
    }
    // bias + ELU
    float xf[16];
    {
        const float4* bp0 = (const float4*)(b1 + lane * 8);
        const float4* bp1 = (const float4*)(b1 + 512 + lane * 8);
        float4 c0 = bp0[0], c1 = bp0[1], c2 = bp1[0], c3 = bp1[1];
        float bb[16] = {c0.x,c0.y,c0.z,c0.w, c1.x,c1.y,c1.z,c1.w,
                        c2.x,c2.y,c2.z,c2.w, c3.x,c3.y,c3.z,c3.w};
#pragma unroll
        for (int i = 0; i < 16; i++) {
            float v = acc[i] + bb[i];
            xf[i] = (v > 0.f) ? v : (expf(v) - 1.f);
        }
    }
    // projection to 21 outputs, wave-local reduce
    float a2 = 0.f;
    for (int c = 0; c < 21; c++) {
        const float* wr = (c < CO) ? Ws2 + (size_t)c * HID : wd2v;
        const float4* w0 = (const float4*)(wr + lane * 8);
        const float4* w1 = (const float4*)(wr + 512 + lane * 8);
        float4 wa = w0[0], wb = w0[1], wc = w1[0], wd = w1[1];
        float dp = xf[0]*wa.x + xf[1]*wa.y + xf[2]*wa.z + xf[3]*wa.w
                 + xf[4]*wb.x + xf[5]*wb.y + xf[6]*wb.z + xf[7]*wb.w
                 + xf[8]*wc.x + xf[9]*wc.y + xf[10]*wc.z + xf[11]*wc.w
                 + xf[12]*wd.x + xf[13]*wd.y + xf[14]*wd.z + xf[15]*wd.w;
        for (int o = 32; o; o >>= 1) dp += __shfl_xor(dp, o, 64);
        if (c < CO) {
            if (lane == 0) H2[(size_t)n * CO + c] = dp;
            a2 += dp * as2[c];
        } else if (lane == 0) a_dst2[n] = dp;
    }
    if (lane == 0) a_src2[n] = a2;
}

// ------- fused: edge softmax (alpha2) + layer-2 agg + bias + final out0 -------
// Wave-per-node; half-waves MAC even/odd edges; epilogue applies the class-softmax
// scaling (ext row, gmax/ginv) and writes out[n*CO+c] directly (ms1T eliminated).
__global__ __launch_bounds__(64) void k_agg2(const int* __restrict__ offs,
                                             const int* __restrict__ csr,
                                             const float* __restrict__ a_src,
                                             const float* __restrict__ a_dst,
                                             const float* __restrict__ H2,
                                             const float* __restrict__ b2,
                                             const float* __restrict__ ext,
                                             const float* __restrict__ gmax,
                                             const float* __restrict__ ginv,
                                             float* __restrict__ out) {
    int n = blockIdx.x, lane = threadIdx.x;
    int b = offs[n], deg = offs[n + 1] - b;
    float ad = a_dst[n];
    __shared__ int   sc[128];
    __shared__ float av[128];
    bool small = (deg <= 128);
    float gm, inv;
    if (small) {
        float mymax = -INFINITY;
        for (int j = lane; j < deg; j += 64) {
            int s = csr[b + j];
            float v = a_src[s] + ad;
            v = (v >= 0.f) ? v : 0.2f * v;
            sc[j] = s; av[j] = v;
            mymax = fmaxf(mymax, v);
        }
        for (int o = 32; o; o >>= 1) mymax = fmaxf(mymax, __shfl_xor(mymax, o, 64));
        gm = mymax;
        float mysum = 0.f;
        for (int j = lane; j < deg; j += 64) {
            float e = expf(av[j] - gm);
            av[j] = e;
            mysum += e;
        }
        for (int o = 32; o; o >>= 1) mysum += __shfl_xor(mysum, o, 64);
        inv = 1.0f / (mysum + 1e-16f);
        for (int j = lane; j < deg; j += 64) av[j] *= inv;
        __syncthreads();
    } else {
        float mymax = -INFINITY;
        for (int j = lane; j < deg; j += 64) {
            float v = a_src[csr[b + j]] + ad;
            v = (v >= 0.f) ? v : 0.2f * v;
            mymax = fmaxf(mymax, v);
        }
        for (int o = 32; o; o >>= 1) mymax = fmaxf(mymax, __shfl_xor(mymax, o, 64));
        gm = mymax;
        float mysum = 0.f;
        for (int j = lane; j < deg; j += 64) {
            float v = a_src[csr[b + j]] + ad;
            v = (v >= 0.f) ? v : 0.2f * v;
            mysum += expf(v - gm);
        }
        for (int o = 32; o; o >>= 1) mysum += __shfl_xor(mysum, o, 64);
        inv = 1.0f / (mysum + 1e-16f);
    }
    int h = lane >> 5, c = lane & 31;
    float acc = 0.f;
    for (int base = 0; base < deg; base += 128) {
        int lim = deg - base; if (lim > 128) lim = 128;
        if (!small) {
            __syncthreads();
            for (int j = lane; j < lim; j += 64) {
                int s = csr[b + base + j];
                float v = a_src[s] + ad;
                v = (v >= 0.f) ? v : 0.2f * v;
                sc[j] = s; av[j] = expf(v - gm) * inv;
            }
            __syncthreads();
        }
        if (c < CO)
            for (int j = h; j < lim; j += 2)
                acc += av[j] * H2[(size_t)sc[j] * CO + c];
    }
    acc += __shfl_xor(acc, 32, 64);
    if (h == 0 && c < CO) {
        float ms1 = acc + b2[c];
        float o = expf(ext[(size_t)c * NN + n] - gmax[c]) * ginv[c] * ms1;
        out[(size_t)n * CO + c] = o;
    }
}

extern "C" void kernel_launch(void* const* d_in, const int* in_sizes, int n_in,
                              void* d_out, int out_size, void* d_ws, size_t ws_size,
                              hipStream_t stream) {
    const float* x   = (const float*)d_in[0];
    const int*   edg = (const int*)d_in[1];
    const float* W0  = (const float*)d_in[2];
    const float* Ws1 = (const float*)d_in[4];
    const float* Wd1 = (const float*)d_in[5];
    const float* as1 = (const float*)d_in[6];
    const float* ad1 = (const float*)d_in[7];
    const float* b1  = (const float*)d_in[8];
    const float* Ws2 = (const float*)d_in[9];
    const float* Wd2 = (const float*)d_in[10];
    const float* as2 = (const float*)d_in[11];
    const float* ad2 = (const float*)d_in[12];
    const float* b2  = (const float*)d_in[13];
    float* out = (float*)d_out;

    char* p = (char*)d_ws;
    auto alloc = [&](size_t bytes) -> char* {
        char* r = p; p += (bytes + 511) & ~((size_t)511); return r;
    };
    unsigned short* xb   = (unsigned short*)alloc((size_t)NN * FIN * 2);   // 81.9 MB
    unsigned short* Bext = (unsigned short*)alloc((size_t)NBV * FIN * 2);  //  8.6 MB
    unsigned short* H1   = (unsigned short*)alloc((size_t)NN * HID * 2);   // 20.5 MB
    float* ext    = (float*)alloc((size_t)22 * NN * 4);   // ms0T rows 0..19, a_src1=20, a_dst1=21
    float* partS  = (float*)alloc((size_t)8 * FIN * 4);
    float* partD  = (float*)alloc((size_t)8 * FIN * 4);
    float* wd2v   = (float*)alloc(HID * 4);
    float* H2     = (float*)alloc((size_t)NN * CO * 4);
    float* a_src2 = (float*)alloc(NN * 4);
    float* a_dst2 = (float*)alloc(NN * 4);
    int* csr_src  = (int*)alloc((size_t)ET * 4);
    int* cnt      = (int*)alloc(NN * 4);
    int* offs     = (int*)alloc((NN + 1) * 4);
    int* cursor   = (int*)alloc(NN * 4);
    int* eflag    = (int*)alloc(64);
    float* gmax   = (float*)alloc(CO * 4);
    float* ginv   = (float*)alloc(CO * 4);

    k_cast<<<NN * FIN / 8 / 256, 256, 0, stream>>>(x, xb, edg, cnt, eflag);
    k_prep<<<BEXTB + 128 + CNTB, 256, 0, stream>>>(Ws1, Wd1, W0, as1, ad1,
                                                   Bext, partS, partD, edg, eflag, cnt);
    k_vred<<<FIN / 256, 256, 0, stream>>>(partS, partD, Wd2, ad2, Bext, wd2v);
    k_gemm_ext<<<NWG, 256, 0, stream>>>(xb, Bext, H1, ext, NN);
    k_scan<<<1, 1024, 0, stream>>>(cnt, offs, cursor);
    k_scatter<<<CNTB + CO, 256, 0, stream>>>(edg, eflag, cursor, csr_src,
                                             ext, gmax, ginv, out);
    k_agg1f<<<NN, 64, 0, stream>>>(offs, csr_src, ext + 20 * NN, ext + 21 * NN, H1,
                                   b1, Ws2, wd2v, as2, H2, a_src2, a_dst2);
    k_agg2<<<NN, 64, 0, stream>>>(offs, csr_src, a_src2, a_dst2, H2, b2,
                                  ext, gmax, ginv, out);
}